// Round 15
// baseline (53.737 us; speedup 1.0000x reference)
//
#include <hip/hip_runtime.h>
#include <hip/hip_bf16.h>

typedef __bf16 bf16;
typedef __attribute__((ext_vector_type(4))) __bf16 bf16x4;
typedef __attribute__((ext_vector_type(8))) __bf16 bf16x8;
typedef __attribute__((ext_vector_type(4))) float f32x4;

#define D_MODEL 1024
#define DK 128
#define LSEQ 2048
#define NQT 128
#define NB 4
// 1/sqrt(128) * log2(e): softmax runs in exp2 domain end-to-end
#define SCALE2 (0.08838834764831845f * 1.4426950408889634f)

#define GLD16(g, l) __builtin_amdgcn_global_load_lds(                       \
    (const __attribute__((address_space(1))) void*)(g),                     \
    (__attribute__((address_space(3))) void*)(l), 16, 0, 0)

// ---------------------------------------------------------------------------
// Kernel 0: transpose + bf16-convert weights. W[1024][128] f32 -> Wt[3][128][1024]
// (R9-proven, unchanged)
// ---------------------------------------------------------------------------
__global__ __launch_bounds__(256) void wt_kernel(
    const float* __restrict__ Wq, const float* __restrict__ Wk,
    const float* __restrict__ Wv, bf16* __restrict__ Wt)
{
    __shared__ bf16 tile[64][72];
    const float* W = (blockIdx.z == 0) ? Wq : (blockIdx.z == 1) ? Wk : Wv;
    int k0 = blockIdx.x * 64;
    int n0 = blockIdx.y * 64;
    int t  = threadIdx.x;
    #pragma unroll
    for (int i = 0; i < 16; ++i) {
        int idx = t + i * 256;
        int r = idx >> 6, c = idx & 63;
        tile[c][r] = (bf16)W[(size_t)(k0 + r) * DK + n0 + c];
    }
    __syncthreads();
    bf16* out = Wt + (size_t)blockIdx.z * DK * D_MODEL;
    #pragma unroll
    for (int i = 0; i < 16; ++i) {
        int idx = t + i * 256;
        int rr = idx >> 6, cc = idx & 63;
        out[(size_t)(n0 + rr) * D_MODEL + k0 + cc] = tile[rr][cc];
    }
}

// ---------------------------------------------------------------------------
// Kernel 1: QKV projection GEMM (R9-proven body). X f32 x Wt bf16, M-tile 64,
// BK 64, 4 waves; reg-staged double-buffer, f32->bf16 on LDS store.
// Epilogue: Kb and Vt written PRE-SWIZZLED (16B granule ^= token-row&7 / d&7
// within 128B groups) so attn's global_load_lds into LINEAR LDS + XOR-read is
// bank-conflict-free (rule 21; mechanics proven correct in R6).
// ---------------------------------------------------------------------------
__global__ __launch_bounds__(256) void proj_kernel(
    const float* __restrict__ X, const bf16* __restrict__ Wt,
    bf16* __restrict__ Qs, bf16* __restrict__ Kb, bf16* __restrict__ Vt)
{
    __shared__ bf16 Xs[64][72];
    __shared__ bf16 Ws[128][72];
    int mt = blockIdx.x, mat = blockIdx.y;
    const bf16* W = Wt + (size_t)mat * DK * D_MODEL;
    int t = threadIdx.x;
    int wave = t >> 6, lane = t & 63;
    int lq = lane & 15, g = lane >> 4;
    int row0 = mt * 64;

    f32x4 acc[4][2];
    #pragma unroll
    for (int m = 0; m < 4; ++m)
        #pragma unroll
        for (int n = 0; n < 2; ++n) acc[m][n] = f32x4{0.f, 0.f, 0.f, 0.f};

    f32x4  rxf[4];
    bf16x8 rw[4];
    auto LOADR = [&](int k0) {
        #pragma unroll
        for (int i = 0; i < 4; ++i) {
            int u = t + i * 256, r = u >> 4, c4 = u & 15;
            rxf[i] = *reinterpret_cast<const f32x4*>(
                &X[(size_t)(row0 + r) * D_MODEL + k0 + c4 * 4]);
        }
        #pragma unroll
        for (int i = 0; i < 4; ++i) {
            int u = t + i * 256, r = u >> 3, c8 = u & 7;
            rw[i] = *reinterpret_cast<const bf16x8*>(
                &W[(size_t)r * D_MODEL + k0 + c8 * 8]);
        }
    };
    auto STORER = [&]() {
        #pragma unroll
        for (int i = 0; i < 4; ++i) {
            int u = t + i * 256, r = u >> 4, c4 = u & 15;
            bf16x4 h;
            h[0]=(bf16)rxf[i][0]; h[1]=(bf16)rxf[i][1];
            h[2]=(bf16)rxf[i][2]; h[3]=(bf16)rxf[i][3];
            *reinterpret_cast<bf16x4*>(&Xs[r][c4 * 4]) = h;
        }
        #pragma unroll
        for (int i = 0; i < 4; ++i) {
            int u = t + i * 256, r = u >> 3, c8 = u & 7;
            *reinterpret_cast<bf16x8*>(&Ws[r][c8 * 8]) = rw[i];
        }
    };

    LOADR(0);
    for (int ks = 0; ks < 16; ++ks) {
        __syncthreads();
        STORER();
        if (ks + 1 < 16) LOADR((ks + 1) * 64);
        __syncthreads();
        #pragma unroll
        for (int kk = 0; kk < 2; ++kk) {
            bf16x8 a[4];
            #pragma unroll
            for (int mr = 0; mr < 4; ++mr)
                a[mr] = *reinterpret_cast<const bf16x8*>(&Xs[mr * 16 + lq][kk * 32 + g * 8]);
            #pragma unroll
            for (int n = 0; n < 2; ++n) {
                bf16x8 bfr = *reinterpret_cast<const bf16x8*>(
                    &Ws[wave * 32 + n * 16 + lq][kk * 32 + g * 8]);
                #pragma unroll
                for (int mr = 0; mr < 4; ++mr)
                    acc[mr][n] = __builtin_amdgcn_mfma_f32_16x16x32_bf16(a[mr], bfr, acc[mr][n], 0, 0, 0);
            }
        }
    }
    #pragma unroll
    for (int mr = 0; mr < 4; ++mr) {
        int orow = row0 + mr * 16 + g * 4;
        #pragma unroll
        for (int n = 0; n < 2; ++n) {
            int col = wave * 32 + n * 16 + lq;
            if (mat == 0) {
                #pragma unroll
                for (int r = 0; r < 4; ++r)
                    Qs[(size_t)(orow + r) * DK + col] = (bf16)(acc[mr][n][r] * SCALE2);
            } else if (mat == 1) {
                // K pre-swizzled: 16B granule (col>>3) ^= (token&7)
                int colg = col >> 3, cre = col & 7;
                #pragma unroll
                for (int r = 0; r < 4; ++r) {
                    int row = orow + r;    // token (kv)
                    Kb[(size_t)row * DK + ((colg ^ (row & 7)) << 3) + cre]
                        = (bf16)acc[mr][n][r];
                }
            } else {
                // V^T pre-swizzled within each 64-kv group: granule ^= d&7
                int bb  = orow >> 11;
                int kv0 = orow & 2047;     // multiple of 4; 4-span stays in granule
                int gv  = ((kv0 & 63) >> 3) ^ (col & 7);
                bf16x4 h;
                h[0]=(bf16)acc[mr][n][0]; h[1]=(bf16)acc[mr][n][1];
                h[2]=(bf16)acc[mr][n][2]; h[3]=(bf16)acc[mr][n][3];
                *reinterpret_cast<bf16x4*>(
                    &Vt[((size_t)bb * DK + col) * LSEQ + (kv0 & ~63) + (gv << 3) + (kv0 & 7)]) = h;
            }
        }
    }
}

// ---------------------------------------------------------------------------
// Kernel 2: causal flash attention — 128-thr / 2-wave blocks, 64 q-rows
// (wave = 32 rows via TWO 16-row fragments sharing every K/V fragment read).
// K/V staged by global_load_lds into LINEAR LDS (sources pre-swizzled in
// global; reads apply the same XOR -> conflict-free b128). Schedule, grid,
// XCD decode, split epilogue identical to R14.
// ---------------------------------------------------------------------------
__global__ __launch_bounds__(128, 2) void attn_kernel(
    const bf16* __restrict__ Qs, const bf16* __restrict__ Kb,
    const bf16* __restrict__ Vt, bf16* __restrict__ Zp,
    float* __restrict__ Mp, float* __restrict__ Lp,
    float* __restrict__ Out, int split)
{
    __shared__ __align__(16) bf16 Ks[64][128];
    __shared__ __align__(16) bf16 Vs[128][64];
    __shared__ bf16 P[2][32][72];

    int bid = blockIdx.x;
    int b, qblk, s;
    if (split) {
        int xcd = bid & 7, u = bid >> 3;      // u in [0,72)
        b = xcd >> 1;                         // XCD-pinned batch (KV L2-fit)
        int n2 = (u << 1) | (xcd & 1);        // interleave: balance XCD halves
        int q = 0, off = 0;
        while (off + ((q >> 2) + 1) <= n2) { off += (q >> 2) + 1; ++q; }
        qblk = q;
        s = n2 - off;
    } else {
        b = bid >> 5;
        qblk = bid & 31;
        s = 0;
    }
    int t = threadIdx.x;
    int wave = t >> 6, lane = t & 63;
    int lq = lane & 15, g = lane >> 4;
    int key = lq & 7;
    int qg0 = qblk * 64 + wave * 32 + lq;     // fragment 0 q-row
    int qg1 = qg0 + 16;                       // fragment 1 q-row

    int nt = qblk + 1;                        // 64-kv tiles
    int t0 = split ? 4 * s : 0;
    int t1 = split ? min(4 * s + 4, nt) : nt;

    const bf16* Kbase = Kb + (size_t)b * LSEQ * DK;
    const bf16* Vbase = Vt + (size_t)b * DK * LSEQ;

    const bf16* Qrow0 = Qs + ((size_t)b * LSEQ + qg0) * DK;
    bf16x8 qf0[4], qf1[4];
    #pragma unroll
    for (int ks = 0; ks < 4; ++ks) {
        qf0[ks] = *reinterpret_cast<const bf16x8*>(&Qrow0[ks * 32 + g * 8]);
        qf1[ks] = *reinterpret_cast<const bf16x8*>(&Qrow0[16 * DK + ks * 32 + g * 8]);
    }

    f32x4 z0[8], z1[8];
    #pragma unroll
    for (int i = 0; i < 8; ++i) {
        z0[i] = f32x4{0.f, 0.f, 0.f, 0.f};
        z1[i] = f32x4{0.f, 0.f, 0.f, 0.f};
    }
    float mrun0 = -3.0e38f, lrun0 = 0.f;
    float mrun1 = -3.0e38f, lrun1 = 0.f;

    auto STAGE = [&](int kvb) {
        // K tile: 64 rows x 256B = 16KB contiguous in (pre-swizzled) Kb
        const char* kg = (const char*)(Kbase + (size_t)kvb * DK) + (size_t)t * 16;
        char* kl = (char*)(&Ks[0][0]) + (size_t)t * 16;
        #pragma unroll
        for (int i = 0; i < 8; ++i)
            GLD16(kg + i * 2048, kl + i * 2048);
        // V tile: 128 d-rows x 128B strips (pre-swizzled within 64-kv groups)
        const char* vg = (const char*)Vbase + (size_t)(t >> 3) * (LSEQ * 2)
                       + (size_t)kvb * 2 + (t & 7) * 16;
        char* vl = (char*)(&Vs[0][0]) + (size_t)t * 16;
        #pragma unroll
        for (int i = 0; i < 8; ++i)
            GLD16(vg + (size_t)i * 16 * (LSEQ * 2), vl + i * 2048);
    };

    for (int ti = t0; ti < t1; ++ti) {
        int kvb = ti * 64;
        __syncthreads();              // prev tile's readers done
        STAGE(kvb);                   // async direct-to-LDS
        __syncthreads();              // implicit vmcnt(0): tile visible

        // ---- QK^T: each K fragment read feeds BOTH q-fragments ----
        f32x4 sc0[4], sc1[4];
        #pragma unroll
        for (int jj = 0; jj < 4; ++jj) {
            sc0[jj] = f32x4{0.f, 0.f, 0.f, 0.f};
            sc1[jj] = f32x4{0.f, 0.f, 0.f, 0.f};
        }
        __builtin_amdgcn_s_setprio(1);
        #pragma unroll
        for (int jj = 0; jj < 4; ++jj) {
            const char* kr = (const char*)&Ks[jj * 16 + lq][0];
            #pragma unroll
            for (int ks = 0; ks < 4; ++ks) {
                bf16x8 a = *reinterpret_cast<const bf16x8*>(
                    kr + (((4 * ks + g) ^ key) << 4));
                sc0[jj] = __builtin_amdgcn_mfma_f32_16x16x32_bf16(a, qf0[ks], sc0[jj], 0, 0, 0);
                sc1[jj] = __builtin_amdgcn_mfma_f32_16x16x32_bf16(a, qf1[ks], sc1[jj], 0, 0, 0);
            }
        }
        __builtin_amdgcn_s_setprio(0);

        // ---- mask (diagonal tile only) ----
        float sv0[16], sv1[16];
        if (ti == nt - 1) {
            #pragma unroll
            for (int jj = 0; jj < 4; ++jj)
                #pragma unroll
                for (int r = 0; r < 4; ++r) {
                    int kv0 = kvb + jj * 16 + g * 4 + r;
                    sv0[jj * 4 + r] = (kv0 <= qg0) ? sc0[jj][r] : -3.0e38f;
                    sv1[jj * 4 + r] = (kv0 <= qg1) ? sc1[jj][r] : -3.0e38f;
                }
        } else {
            #pragma unroll
            for (int jj = 0; jj < 4; ++jj)
                #pragma unroll
                for (int r = 0; r < 4; ++r) {
                    sv0[jj * 4 + r] = sc0[jj][r];
                    sv1[jj * 4 + r] = sc1[jj][r];
                }
        }

        // ---- online softmax, fragment 0 ----
        float mt0 = sv0[0], mt1 = sv1[0];
        #pragma unroll
        for (int i = 1; i < 16; ++i) { mt0 = fmaxf(mt0, sv0[i]); mt1 = fmaxf(mt1, sv1[i]); }
        mt0 = fmaxf(mt0, __shfl_xor(mt0, 16));
        mt0 = fmaxf(mt0, __shfl_xor(mt0, 32));
        mt1 = fmaxf(mt1, __shfl_xor(mt1, 16));
        mt1 = fmaxf(mt1, __shfl_xor(mt1, 32));
        if (!__all(mt0 <= mrun0)) {
            float mnew  = fmaxf(mrun0, mt0);
            float alpha = exp2f(mrun0 - mnew);
            lrun0 *= alpha;
            #pragma unroll
            for (int i = 0; i < 8; ++i) {
                z0[i][0] *= alpha; z0[i][1] *= alpha; z0[i][2] *= alpha; z0[i][3] *= alpha;
            }
            mrun0 = mnew;
        }
        if (!__all(mt1 <= mrun1)) {
            float mnew  = fmaxf(mrun1, mt1);
            float alpha = exp2f(mrun1 - mnew);
            lrun1 *= alpha;
            #pragma unroll
            for (int i = 0; i < 8; ++i) {
                z1[i][0] *= alpha; z1[i][1] *= alpha; z1[i][2] *= alpha; z1[i][3] *= alpha;
            }
            mrun1 = mnew;
        }
        float psum0 = 0.f, psum1 = 0.f;
        #pragma unroll
        for (int jj = 0; jj < 4; ++jj) {
            bf16x4 pb0, pb1;
            #pragma unroll
            for (int r = 0; r < 4; ++r) {
                float e0 = exp2f(sv0[jj * 4 + r] - mrun0);
                float e1 = exp2f(sv1[jj * 4 + r] - mrun1);
                psum0 += e0; psum1 += e1;
                pb0[r] = (bf16)e0; pb1[r] = (bf16)e1;
            }
            *reinterpret_cast<bf16x4*>(&P[wave][lq][jj * 16 + g * 4])      = pb0;
            *reinterpret_cast<bf16x4*>(&P[wave][16 + lq][jj * 16 + g * 4]) = pb1;
        }
        psum0 += __shfl_xor(psum0, 16);
        psum0 += __shfl_xor(psum0, 32);
        psum1 += __shfl_xor(psum1, 16);
        psum1 += __shfl_xor(psum1, 32);
        lrun0 += psum0;
        lrun1 += psum1;

        // ---- PV: each V fragment read feeds BOTH q-fragments ----
        __builtin_amdgcn_s_setprio(1);
        #pragma unroll
        for (int sl = 0; sl < 2; ++sl) {
            bf16x8 pf0 = *reinterpret_cast<const bf16x8*>(&P[wave][lq][sl * 32 + g * 8]);
            bf16x8 pf1 = *reinterpret_cast<const bf16x8*>(&P[wave][16 + lq][sl * 32 + g * 8]);
            #pragma unroll
            for (int dt = 0; dt < 8; ++dt) {
                const char* vr = (const char*)&Vs[dt * 16 + lq][0];
                bf16x8 av = *reinterpret_cast<const bf16x8*>(
                    vr + (((4 * sl + g) ^ key) << 4));
                z0[dt] = __builtin_amdgcn_mfma_f32_16x16x32_bf16(av, pf0, z0[dt], 0, 0, 0);
                z1[dt] = __builtin_amdgcn_mfma_f32_16x16x32_bf16(av, pf1, z1[dt], 0, 0, 0);
            }
        }
        __builtin_amdgcn_s_setprio(0);
    }

    int S = (qblk >> 2) + 1;
    if (!split || S == 1) {
        float inv0 = 1.f / lrun0, inv1 = 1.f / lrun1;
        float* o0 = Out + ((size_t)b * LSEQ + qg0) * DK;
        float* o1 = Out + ((size_t)b * LSEQ + qg1) * DK;
        #pragma unroll
        for (int dt = 0; dt < 8; ++dt) {
            f32x4 v0, v1;
            v0[0]=z0[dt][0]*inv0; v0[1]=z0[dt][1]*inv0; v0[2]=z0[dt][2]*inv0; v0[3]=z0[dt][3]*inv0;
            v1[0]=z1[dt][0]*inv1; v1[1]=z1[dt][1]*inv1; v1[2]=z1[dt][2]*inv1; v1[3]=z1[dt][3]*inv1;
            *reinterpret_cast<f32x4*>(&o0[dt * 16 + g * 4]) = v0;
            *reinterpret_cast<f32x4*>(&o1[dt * 16 + g * 4]) = v1;
        }
    } else {
        int qw0 = qblk * 4 + wave * 2;                  // 16-row tile ids qw0, qw0+1
        size_t T0 = ((size_t)(b * NQT + qw0)     * 8 + s);
        size_t T1 = ((size_t)(b * NQT + qw0 + 1) * 8 + s);
        bf16* zp0 = Zp + T0 * (16 * 128);
        bf16* zp1 = Zp + T1 * (16 * 128);
        #pragma unroll
        for (int dt = 0; dt < 8; ++dt) {
            bf16x4 h0, h1;
            h0[0]=(bf16)z0[dt][0]; h0[1]=(bf16)z0[dt][1]; h0[2]=(bf16)z0[dt][2]; h0[3]=(bf16)z0[dt][3];
            h1[0]=(bf16)z1[dt][0]; h1[1]=(bf16)z1[dt][1]; h1[2]=(bf16)z1[dt][2]; h1[3]=(bf16)z1[dt][3];
            *reinterpret_cast<bf16x4*>(&zp0[lq * 128 + dt * 16 + g * 4]) = h0;
            *reinterpret_cast<bf16x4*>(&zp1[lq * 128 + dt * 16 + g * 4]) = h1;
        }
        if (g == 0) {
            Mp[T0 * 16 + lq] = mrun0;
            Lp[T0 * 16 + lq] = lrun0;
            Mp[T1 * 16 + lq] = mrun1;
            Lp[T1 * 16 + lq] = lrun1;
        }
    }
}

// ---------------------------------------------------------------------------
// Kernel 3: merge split-KV partials (bf16 Zp). qt<16 stored directly by attn
// -> grid covers qt 16..127. S(qt) = (qt>>4)+1 >= 2. (R14-proven, unchanged)
// ---------------------------------------------------------------------------
__global__ __launch_bounds__(256) void combine_kernel(
    const bf16* __restrict__ Zp, const float* __restrict__ Mp,
    const float* __restrict__ Lp, float* __restrict__ Out)
{
    int qt = blockIdx.x + 16, b = blockIdx.y;
    int S  = (qt >> 4) + 1;
    int t  = threadIdx.x;
    int r  = t >> 4;
    int d0 = (t & 15) * 8;
    size_t Tbase = (size_t)(b * NQT + qt) * 8;

    float m = -3.0e38f;
    for (int s = 0; s < S; ++s)
        m = fmaxf(m, Mp[(Tbase + s) * 16 + r]);

    float L = 0.f;
    float a[8] = {0.f, 0.f, 0.f, 0.f, 0.f, 0.f, 0.f, 0.f};
    for (int s = 0; s < S; ++s) {
        float w = exp2f(Mp[(Tbase + s) * 16 + r] - m);
        L += w * Lp[(Tbase + s) * 16 + r];
        bf16x8 v = *reinterpret_cast<const bf16x8*>(
            &Zp[(Tbase + s) * (16 * 128) + r * 128 + d0]);
        #pragma unroll
        for (int j = 0; j < 8; ++j) a[j] += w * (float)v[j];
    }
    float inv = 1.f / L;
    float* orow = Out + ((size_t)b * LSEQ + qt * 16 + r) * DK + d0;
    f32x4 o0, o1;
    o0[0]=a[0]*inv; o0[1]=a[1]*inv; o0[2]=a[2]*inv; o0[3]=a[3]*inv;
    o1[0]=a[4]*inv; o1[1]=a[5]*inv; o1[2]=a[6]*inv; o1[3]=a[7]*inv;
    *reinterpret_cast<f32x4*>(&orow[0]) = o0;
    *reinterpret_cast<f32x4*>(&orow[4]) = o1;
}

// ---------------------------------------------------------------------------
extern "C" void kernel_launch(void* const* d_in, const int* in_sizes, int n_in,
                              void* d_out, int out_size, void* d_ws, size_t ws_size,
                              hipStream_t stream)
{
    const float* X  = (const float*)d_in[0];
    const float* Wq = (const float*)d_in[1];
    const float* Wk = (const float*)d_in[2];
    const float* Wv = (const float*)d_in[3];
    float* Out = (float*)d_out;

    char* ws = (char*)d_ws;
    // layout: Wt @0 (768KB) ; Qs @1MB ; Kb @3MB ; Vt @5MB ; Zp @7MB (16MB bf16) ;
    //         Mp / Lp after (256KB each). Total ~23.5MB.
    bf16* Wt = (bf16*)(ws);
    bf16* Qs = (bf16*)(ws + ((size_t)1 << 20));
    bf16* Kb = (bf16*)(ws + ((size_t)3 << 20));
    bf16* Vt = (bf16*)(ws + ((size_t)5 << 20));
    size_t base = (size_t)7 << 20;

    size_t zp_bytes = (size_t)NB * NQT * 8 * 16 * 128 * 2;   // 16 MB (bf16)
    size_t ml_bytes = (size_t)NB * NQT * 8 * 16 * 4;         // 256 KB each
    int split = (ws_size >= base + zp_bytes + 2 * ml_bytes) ? 1 : 0;

    bf16*  Zp = (bf16*)(ws + base);
    float* Mp = (float*)(ws + base + zp_bytes);
    float* Lp = (float*)(ws + base + zp_bytes + ml_bytes);

    hipLaunchKernelGGL(wt_kernel,   dim3(16, 2, 3), dim3(256), 0, stream, Wq, Wk, Wv, Wt);
    hipLaunchKernelGGL(proj_kernel, dim3(128, 3),   dim3(256), 0, stream, X, Wt, Qs, Kb, Vt);
    hipLaunchKernelGGL(attn_kernel, dim3(split ? 576 : NB * 32), dim3(128), 0, stream,
                       Qs, Kb, Vt, Zp, Mp, Lp, Out, split);
    if (split)
        hipLaunchKernelGGL(combine_kernel, dim3(112, NB), dim3(256), 0, stream,
                           Zp, Mp, Lp, Out);
}

// Round 16
// 50.449 us; speedup vs baseline: 1.0652x; 1.0652x over previous
//
#include <hip/hip_runtime.h>
#include <hip/hip_bf16.h>

typedef __bf16 bf16;
typedef __attribute__((ext_vector_type(4))) __bf16 bf16x4;
typedef __attribute__((ext_vector_type(8))) __bf16 bf16x8;
typedef __attribute__((ext_vector_type(4))) float f32x4;

#define D_MODEL 1024
#define DK 128
#define LSEQ 2048
#define NQT 128
#define NB 4
// 1/sqrt(128) * log2(e): softmax runs in exp2 domain end-to-end
#define SCALE2 (0.08838834764831845f * 1.4426950408889634f)

// ---------------------------------------------------------------------------
// Kernel 0: transpose + bf16-convert weights. W[1024][128] f32 -> Wt[3][128][1024]
// ---------------------------------------------------------------------------
__global__ __launch_bounds__(256) void wt_kernel(
    const float* __restrict__ Wq, const float* __restrict__ Wk,
    const float* __restrict__ Wv, bf16* __restrict__ Wt)
{
    __shared__ bf16 tile[64][72];
    const float* W = (blockIdx.z == 0) ? Wq : (blockIdx.z == 1) ? Wk : Wv;
    int k0 = blockIdx.x * 64;
    int n0 = blockIdx.y * 64;
    int t  = threadIdx.x;
    #pragma unroll
    for (int i = 0; i < 16; ++i) {
        int idx = t + i * 256;
        int r = idx >> 6, c = idx & 63;
        tile[c][r] = (bf16)W[(size_t)(k0 + r) * DK + n0 + c];
    }
    __syncthreads();
    bf16* out = Wt + (size_t)blockIdx.z * DK * D_MODEL;
    #pragma unroll
    for (int i = 0; i < 16; ++i) {
        int idx = t + i * 256;
        int rr = idx >> 6, cc = idx & 63;
        out[(size_t)(n0 + rr) * D_MODEL + k0 + cc] = tile[rr][cc];
    }
}

// ---------------------------------------------------------------------------
// Kernel 1: QKV projection GEMM (R5/R9-proven). X f32 x Wt bf16, M-tile 64,
// BK 64, 4 waves; reg-staged double-buffer, f32->bf16 on LDS store.
// [.][72] pads: word-stride ≡ 4 (mod 32) -> b128 reads already at bank floor.
// ---------------------------------------------------------------------------
__global__ __launch_bounds__(256) void proj_kernel(
    const float* __restrict__ X, const bf16* __restrict__ Wt,
    bf16* __restrict__ Qs, bf16* __restrict__ Kb, bf16* __restrict__ Vt)
{
    __shared__ bf16 Xs[64][72];
    __shared__ bf16 Ws[128][72];
    int mt = blockIdx.x, mat = blockIdx.y;
    const bf16* W = Wt + (size_t)mat * DK * D_MODEL;
    int t = threadIdx.x;
    int wave = t >> 6, lane = t & 63;
    int lq = lane & 15, g = lane >> 4;
    int row0 = mt * 64;

    f32x4 acc[4][2];
    #pragma unroll
    for (int m = 0; m < 4; ++m)
        #pragma unroll
        for (int n = 0; n < 2; ++n) acc[m][n] = f32x4{0.f, 0.f, 0.f, 0.f};

    f32x4  rxf[4];
    bf16x8 rw[4];
    auto LOADR = [&](int k0) {
        #pragma unroll
        for (int i = 0; i < 4; ++i) {
            int u = t + i * 256, r = u >> 4, c4 = u & 15;
            rxf[i] = *reinterpret_cast<const f32x4*>(
                &X[(size_t)(row0 + r) * D_MODEL + k0 + c4 * 4]);
        }
        #pragma unroll
        for (int i = 0; i < 4; ++i) {
            int u = t + i * 256, r = u >> 3, c8 = u & 7;
            rw[i] = *reinterpret_cast<const bf16x8*>(
                &W[(size_t)r * D_MODEL + k0 + c8 * 8]);
        }
    };
    auto STORER = [&]() {
        #pragma unroll
        for (int i = 0; i < 4; ++i) {
            int u = t + i * 256, r = u >> 4, c4 = u & 15;
            bf16x4 h;
            h[0]=(bf16)rxf[i][0]; h[1]=(bf16)rxf[i][1];
            h[2]=(bf16)rxf[i][2]; h[3]=(bf16)rxf[i][3];
            *reinterpret_cast<bf16x4*>(&Xs[r][c4 * 4]) = h;
        }
        #pragma unroll
        for (int i = 0; i < 4; ++i) {
            int u = t + i * 256, r = u >> 3, c8 = u & 7;
            *reinterpret_cast<bf16x8*>(&Ws[r][c8 * 8]) = rw[i];
        }
    };

    LOADR(0);
    for (int ks = 0; ks < 16; ++ks) {
        __syncthreads();
        STORER();
        if (ks + 1 < 16) LOADR((ks + 1) * 64);
        __syncthreads();
        #pragma unroll
        for (int kk = 0; kk < 2; ++kk) {
            bf16x8 a[4];
            #pragma unroll
            for (int mr = 0; mr < 4; ++mr)
                a[mr] = *reinterpret_cast<const bf16x8*>(&Xs[mr * 16 + lq][kk * 32 + g * 8]);
            #pragma unroll
            for (int n = 0; n < 2; ++n) {
                bf16x8 bfr = *reinterpret_cast<const bf16x8*>(
                    &Ws[wave * 32 + n * 16 + lq][kk * 32 + g * 8]);
                #pragma unroll
                for (int mr = 0; mr < 4; ++mr)
                    acc[mr][n] = __builtin_amdgcn_mfma_f32_16x16x32_bf16(a[mr], bfr, acc[mr][n], 0, 0, 0);
            }
        }
    }
    #pragma unroll
    for (int mr = 0; mr < 4; ++mr) {
        int orow = row0 + mr * 16 + g * 4;
        #pragma unroll
        for (int n = 0; n < 2; ++n) {
            int col = wave * 32 + n * 16 + lq;
            if (mat == 0) {
                #pragma unroll
                for (int r = 0; r < 4; ++r)
                    Qs[(size_t)(orow + r) * DK + col] = (bf16)(acc[mr][n][r] * SCALE2);
            } else if (mat == 1) {
                #pragma unroll
                for (int r = 0; r < 4; ++r)
                    Kb[(size_t)(orow + r) * DK + col] = (bf16)acc[mr][n][r];
            } else {
                int bb  = orow >> 11;
                int kv0 = orow & 2047;
                bf16x4 h;
                h[0]=(bf16)acc[mr][n][0]; h[1]=(bf16)acc[mr][n][1];
                h[2]=(bf16)acc[mr][n][2]; h[3]=(bf16)acc[mr][n][3];
                *reinterpret_cast<bf16x4*>(
                    &Vt[((size_t)bb * DK + col) * LSEQ + kv0]) = h;
            }
        }
    }
}

// ---------------------------------------------------------------------------
// Kernel 2: causal flash attention (R9 body; R14 epilogue).
// Variable KV-split: qblk q -> S(q)=(q>>2)+1 chunks of <=4 tiles, 576 blocks,
// XCD-pinned batch, interleaved halves. Epilogue: S==1 (qblk<4) writes Out
// directly; others write bf16 partials.
// ---------------------------------------------------------------------------
__global__ __launch_bounds__(256, 3) void attn_kernel(
    const bf16* __restrict__ Qs, const bf16* __restrict__ Kb,
    const bf16* __restrict__ Vt, bf16* __restrict__ Zp,
    float* __restrict__ Mp, float* __restrict__ Lp,
    float* __restrict__ Out, int split)
{
    __shared__ bf16 Ks[64][136];
    __shared__ bf16 Vs[128][72];
    __shared__ bf16 P[4][16][72];
    int bid = blockIdx.x;
    int b, qblk, s;
    if (split) {
        int xcd = bid & 7, u = bid >> 3;      // u in [0,72)
        b = xcd >> 1;                         // XCD-pinned batch (KV L2-fit)
        int n2 = (u << 1) | (xcd & 1);        // interleave: balance XCD halves
        int q = 0, off = 0;
        while (off + ((q >> 2) + 1) <= n2) { off += (q >> 2) + 1; ++q; }
        qblk = q;
        s = n2 - off;
    } else {
        b = bid >> 5;
        qblk = bid & 31;
        s = 0;
    }
    int t = threadIdx.x;
    int wave = t >> 6, lane = t & 63;
    int lq = lane & 15, g = lane >> 4;
    int qw16 = qblk * 4 + wave;
    int qg = qw16 * 16 + lq;

    int nt = qblk + 1;                   // 64-kv tiles, same for all 4 waves
    int t0 = split ? 4 * s : 0;
    int t1 = split ? min(4 * s + 4, nt) : nt;

    const bf16* Kbase = Kb + (size_t)b * LSEQ * DK;
    const bf16* Vbase = Vt + (size_t)b * DK * LSEQ;

    const bf16* Qrow = Qs + ((size_t)b * LSEQ + qg) * DK;
    bf16x8 qf[4];
    #pragma unroll
    for (int ks = 0; ks < 4; ++ks)
        qf[ks] = *reinterpret_cast<const bf16x8*>(&Qrow[ks * 32 + g * 8]);

    f32x4 z[8];
    #pragma unroll
    for (int i = 0; i < 8; ++i) z[i] = f32x4{0.f, 0.f, 0.f, 0.f};
    float mrun = -3.0e38f, lrun = 0.f;

    bf16x8 kreg[4], vreg[4];
    auto LOADKV = [&](int kvb) {
        #pragma unroll
        for (int i = 0; i < 4; ++i) {        // K: 64 rows x 16 chunks
            int u = t + i * 256, r = u >> 4, c = u & 15;
            kreg[i] = *reinterpret_cast<const bf16x8*>(
                &Kbase[(size_t)(kvb + r) * DK + c * 8]);
        }
        #pragma unroll
        for (int i = 0; i < 4; ++i) {        // V: 128 rows x 8 chunks
            int u = t + i * 256, d = u >> 3, c = u & 7;
            vreg[i] = *reinterpret_cast<const bf16x8*>(
                &Vbase[(size_t)d * LSEQ + kvb + c * 8]);
        }
    };
    auto STOREKV = [&]() {
        #pragma unroll
        for (int i = 0; i < 4; ++i) {
            int u = t + i * 256, r = u >> 4, c = u & 15;
            *reinterpret_cast<bf16x8*>(&Ks[r][c * 8]) = kreg[i];
        }
        #pragma unroll
        for (int i = 0; i < 4; ++i) {
            int u = t + i * 256, d = u >> 3, c = u & 7;
            *reinterpret_cast<bf16x8*>(&Vs[d][c * 8]) = vreg[i];
        }
    };

    LOADKV(t0 * 64);
    for (int ti = t0; ti < t1; ++ti) {
        int kvb = ti * 64;
        __syncthreads();             // prev tile's readers done
        STOREKV();
        if (ti + 1 < t1) LOADKV((ti + 1) * 64);   // hide under compute
        __syncthreads();             // LDS tile visible

        f32x4 sc[4];
        #pragma unroll
        for (int jj = 0; jj < 4; ++jj) sc[jj] = f32x4{0.f, 0.f, 0.f, 0.f};
        __builtin_amdgcn_s_setprio(1);
        #pragma unroll
        for (int jj = 0; jj < 4; ++jj)
            #pragma unroll
            for (int ks = 0; ks < 4; ++ks) {
                bf16x8 a = *reinterpret_cast<const bf16x8*>(
                    &Ks[jj * 16 + lq][ks * 32 + g * 8]);
                sc[jj] = __builtin_amdgcn_mfma_f32_16x16x32_bf16(a, qf[ks], sc[jj], 0, 0, 0);
            }
        __builtin_amdgcn_s_setprio(0);

        float sv[16];
        if (ti == nt - 1) {          // only the diagonal tile masks
            #pragma unroll
            for (int jj = 0; jj < 4; ++jj)
                #pragma unroll
                for (int r = 0; r < 4; ++r) {
                    int kv0 = kvb + jj * 16 + g * 4 + r;
                    sv[jj * 4 + r] = (kv0 <= qg) ? sc[jj][r] : -3.0e38f;
                }
        } else {
            #pragma unroll
            for (int jj = 0; jj < 4; ++jj)
                #pragma unroll
                for (int r = 0; r < 4; ++r) sv[jj * 4 + r] = sc[jj][r];
        }
        float mt = sv[0];
        #pragma unroll
        for (int i = 1; i < 16; ++i) mt = fmaxf(mt, sv[i]);
        mt = fmaxf(mt, __shfl_xor(mt, 16));
        mt = fmaxf(mt, __shfl_xor(mt, 32));
        if (!__all(mt <= mrun)) {
            float mnew  = fmaxf(mrun, mt);
            float alpha = exp2f(mrun - mnew);
            lrun *= alpha;
            #pragma unroll
            for (int i = 0; i < 8; ++i) {
                z[i][0] *= alpha; z[i][1] *= alpha; z[i][2] *= alpha; z[i][3] *= alpha;
            }
            mrun = mnew;
        }
        float psum = 0.f;
        #pragma unroll
        for (int jj = 0; jj < 4; ++jj) {
            bf16x4 pb;
            #pragma unroll
            for (int r = 0; r < 4; ++r) {
                float e = exp2f(sv[jj * 4 + r] - mrun);
                psum += e;
                pb[r] = (bf16)e;
            }
            *reinterpret_cast<bf16x4*>(&P[wave][lq][jj * 16 + g * 4]) = pb;
        }
        psum += __shfl_xor(psum, 16);
        psum += __shfl_xor(psum, 32);
        lrun += psum;
        __builtin_amdgcn_s_setprio(1);
        #pragma unroll
        for (int sl = 0; sl < 2; ++sl) {
            bf16x8 pf = *reinterpret_cast<const bf16x8*>(&P[wave][lq][sl * 32 + g * 8]);
            #pragma unroll
            for (int dt = 0; dt < 8; ++dt) {
                bf16x8 av = *reinterpret_cast<const bf16x8*>(
                    &Vs[dt * 16 + lq][sl * 32 + g * 8]);
                z[dt] = __builtin_amdgcn_mfma_f32_16x16x32_bf16(av, pf, z[dt], 0, 0, 0);
            }
        }
        __builtin_amdgcn_s_setprio(0);
    }

    int S = (qblk >> 2) + 1;
    if (!split || S == 1) {
        // this block owns the whole kv range for its rows: write Out directly
        float inv = 1.f / lrun;
        float* orow = Out + ((size_t)b * LSEQ + qg) * DK;
        #pragma unroll
        for (int dt = 0; dt < 8; ++dt) {
            f32x4 v;
            v[0]=z[dt][0]*inv; v[1]=z[dt][1]*inv; v[2]=z[dt][2]*inv; v[3]=z[dt][3]*inv;
            *reinterpret_cast<f32x4*>(&orow[dt * 16 + g * 4]) = v;
        }
    } else {
        size_t T = ((size_t)(b * NQT + qw16) * 8 + s);   // stride 8 slices
        bf16* zp = Zp + T * (16 * 128);
        #pragma unroll
        for (int dt = 0; dt < 8; ++dt) {
            bf16x4 h;
            h[0]=(bf16)z[dt][0]; h[1]=(bf16)z[dt][1];
            h[2]=(bf16)z[dt][2]; h[3]=(bf16)z[dt][3];
            *reinterpret_cast<bf16x4*>(&zp[lq * 128 + dt * 16 + g * 4]) = h;
        }
        if (g == 0) {
            Mp[T * 16 + lq] = mrun;
            Lp[T * 16 + lq] = lrun;
        }
    }
}

// ---------------------------------------------------------------------------
// Kernel 3: merge split-KV partials (bf16 Zp). qblk 0-3 (qt<16) were stored
// directly by attn -> grid covers qt 16..127 only. S(qt) = (qt>>4)+1 >= 2.
// ---------------------------------------------------------------------------
__global__ __launch_bounds__(256) void combine_kernel(
    const bf16* __restrict__ Zp, const float* __restrict__ Mp,
    const float* __restrict__ Lp, float* __restrict__ Out)
{
    int qt = blockIdx.x + 16, b = blockIdx.y;
    int S  = (qt >> 4) + 1;
    int t  = threadIdx.x;
    int r  = t >> 4;
    int d0 = (t & 15) * 8;
    size_t Tbase = (size_t)(b * NQT + qt) * 8;

    float m = -3.0e38f;
    for (int s = 0; s < S; ++s)
        m = fmaxf(m, Mp[(Tbase + s) * 16 + r]);

    float L = 0.f;
    float a[8] = {0.f, 0.f, 0.f, 0.f, 0.f, 0.f, 0.f, 0.f};
    for (int s = 0; s < S; ++s) {
        float w = exp2f(Mp[(Tbase + s) * 16 + r] - m);
        L += w * Lp[(Tbase + s) * 16 + r];
        bf16x8 v = *reinterpret_cast<const bf16x8*>(
            &Zp[(Tbase + s) * (16 * 128) + r * 128 + d0]);
        #pragma unroll
        for (int j = 0; j < 8; ++j) a[j] += w * (float)v[j];
    }
    float inv = 1.f / L;
    float* orow = Out + ((size_t)b * LSEQ + qt * 16 + r) * DK + d0;
    f32x4 o0, o1;
    o0[0]=a[0]*inv; o0[1]=a[1]*inv; o0[2]=a[2]*inv; o0[3]=a[3]*inv;
    o1[0]=a[4]*inv; o1[1]=a[5]*inv; o1[2]=a[6]*inv; o1[3]=a[7]*inv;
    *reinterpret_cast<f32x4*>(&orow[0]) = o0;
    *reinterpret_cast<f32x4*>(&orow[4]) = o1;
}

// ---------------------------------------------------------------------------
extern "C" void kernel_launch(void* const* d_in, const int* in_sizes, int n_in,
                              void* d_out, int out_size, void* d_ws, size_t ws_size,
                              hipStream_t stream)
{
    const float* X  = (const float*)d_in[0];
    const float* Wq = (const float*)d_in[1];
    const float* Wk = (const float*)d_in[2];
    const float* Wv = (const float*)d_in[3];
    float* Out = (float*)d_out;

    char* ws = (char*)d_ws;
    // layout: Wt @0 (768KB) ; Qs @1MB ; Kb @3MB ; Vt @5MB ; Zp @7MB (16MB bf16) ;
    //         Mp / Lp after (256KB each). Total ~23.5MB.
    bf16* Wt = (bf16*)(ws);
    bf16* Qs = (bf16*)(ws + ((size_t)1 << 20));
    bf16* Kb = (bf16*)(ws + ((size_t)3 << 20));
    bf16* Vt = (bf16*)(ws + ((size_t)5 << 20));
    size_t base = (size_t)7 << 20;

    size_t zp_bytes = (size_t)NB * NQT * 8 * 16 * 128 * 2;   // 16 MB (bf16)
    size_t ml_bytes = (size_t)NB * NQT * 8 * 16 * 4;         // 256 KB each
    int split = (ws_size >= base + zp_bytes + 2 * ml_bytes) ? 1 : 0;

    bf16*  Zp = (bf16*)(ws + base);
    float* Mp = (float*)(ws + base + zp_bytes);
    float* Lp = (float*)(ws + base + zp_bytes + ml_bytes);

    hipLaunchKernelGGL(wt_kernel,   dim3(16, 2, 3), dim3(256), 0, stream, Wq, Wk, Wv, Wt);
    hipLaunchKernelGGL(proj_kernel, dim3(128, 3),   dim3(256), 0, stream, X, Wt, Qs, Kb, Vt);
    hipLaunchKernelGGL(attn_kernel, dim3(split ? 576 : NB * 32), dim3(256), 0, stream,
                       Qs, Kb, Vt, Zp, Mp, Lp, Out, split);
    if (split)
        hipLaunchKernelGGL(combine_kernel, dim3(112, NB), dim3(256), 0, stream,
                           Zp, Mp, Lp, Out);
}